// Round 1
// baseline (202.933 us; speedup 1.0000x reference)
//
#include <hip/hip_runtime.h>
#include <hip/hip_bf16.h>

#define Bq 2
#define Sq 2048
#define Dq 1024
#define Hq 16

typedef __attribute__((ext_vector_type(8))) short short8;
typedef __attribute__((ext_vector_type(4))) float floatx4;
typedef unsigned short ushort_t;

__device__ __forceinline__ ushort_t f2bf(float f) {
    union { float f; unsigned u; } v; v.f = f;
    unsigned u = v.u;
    u += 0x7fffu + ((u >> 16) & 1u);
    return (ushort_t)(u >> 16);
}

// ---------------- fp32 -> bf16 conversion, 8 elems/thread ----------------
__global__ void cvt_f32_bf16(const float* __restrict__ in, ushort_t* __restrict__ out, int n8) {
    int i = blockIdx.x * blockDim.x + threadIdx.x;
    if (i >= n8) return;
    const float4* p = (const float4*)in + (size_t)i * 2;
    float4 a = p[0], b = p[1];
    ushort4 lo, hi;
    lo.x = f2bf(a.x); lo.y = f2bf(a.y); lo.z = f2bf(a.z); lo.w = f2bf(a.w);
    hi.x = f2bf(b.x); hi.y = f2bf(b.y); hi.z = f2bf(b.z); hi.w = f2bf(b.w);
    *(ushort4*)(out + (size_t)i * 8)     = lo;
    *(ushort4*)(out + (size_t)i * 8 + 4) = hi;
}

// ---------------- RoPE cos/sin tables: [S][32] ----------------
__global__ void rope_tables(float* __restrict__ cost, float* __restrict__ sint) {
    int i = blockIdx.x * blockDim.x + threadIdx.x;
    if (i >= Sq * 32) return;
    int s = i >> 5, f = i & 31;
    float invf = powf(10000.0f, -(float)f / 32.0f);
    float ang = (float)s * invf;
    cost[i] = cosf(ang);
    sint[i] = sinf(ang);
}

// ---------------- QKV projection GEMM (+RoPE for Q/K, transpose-write for V) ----
// A = xb (4096 x 1024, row-major bf16), B^T = W (1024 x 1024 as (N,K) bf16)
// grid: (8, 32, 3)  block: 256
__global__ __launch_bounds__(256, 2) void gemm_qkv(
    const ushort_t* __restrict__ xb,
    const ushort_t* __restrict__ wqb, const ushort_t* __restrict__ wkb, const ushort_t* __restrict__ wvb,
    const float* __restrict__ bq, const float* __restrict__ bk, const float* __restrict__ bv,
    const float* __restrict__ cost, const float* __restrict__ sint,
    ushort_t* __restrict__ qout, ushort_t* __restrict__ kout, ushort_t* __restrict__ vtout)
{
    __shared__ ushort_t As[128 * 32];
    __shared__ ushort_t Bs[128 * 32];
    const int mode = blockIdx.z;
    const ushort_t* W  = (mode == 0) ? wqb : (mode == 1) ? wkb : wvb;
    const float* bias  = (mode == 0) ? bq  : (mode == 1) ? bk  : bv;

    const int t = threadIdx.x;
    const int lane = t & 63;
    const int wid = t >> 6;
    const int l15 = lane & 15, lk = lane >> 4;
    const int wr = wid >> 1, wc = wid & 1;
    const int rowBase = blockIdx.y * 128;
    const int colBase = blockIdx.x * 128;

    floatx4 acc[4][4] = {};

    const char* Ag = (const char*)xb;
    const char* Bg = (const char*)W;

    for (int k0 = 0; k0 < Dq; k0 += 32) {
        __syncthreads();
#pragma unroll
        for (int issue = 0; issue < 2; ++issue) {
            int ldsoff = issue * 4096 + t * 16;
            int row = ldsoff >> 6;     // 64B per LDS row (32 bf16)
            int cb  = ldsoff & 63;
            __builtin_amdgcn_global_load_lds(
                (const __attribute__((address_space(1))) void*)(Ag + (size_t)(rowBase + row) * 2048 + k0 * 2 + cb),
                (__attribute__((address_space(3))) void*)((char*)As + ldsoff), 16, 0, 0);
            __builtin_amdgcn_global_load_lds(
                (const __attribute__((address_space(1))) void*)(Bg + (size_t)(colBase + row) * 2048 + k0 * 2 + cb),
                (__attribute__((address_space(3))) void*)((char*)Bs + ldsoff), 16, 0, 0);
        }
        __syncthreads();

        short8 a[4], b[4];
#pragma unroll
        for (int m = 0; m < 4; ++m)
            a[m] = *(const short8*)((const char*)As + (wr * 64 + m * 16 + l15) * 64 + lk * 16);
#pragma unroll
        for (int n = 0; n < 4; ++n)
            b[n] = *(const short8*)((const char*)Bs + (wc * 64 + n * 16 + l15) * 64 + lk * 16);
#pragma unroll
        for (int m = 0; m < 4; ++m)
#pragma unroll
            for (int n = 0; n < 4; ++n)
                acc[m][n] = __builtin_amdgcn_mfma_f32_16x16x32_bf16(a[m], b[n], acc[m][n], 0, 0, 0);
    }

    const int colW = colBase + wc * 64;   // head-aligned (multiple of 64)
    const int hh = colW >> 6;

    if (mode < 2) {
        ushort_t* outp = (mode == 0) ? qout : kout;
#pragma unroll
        for (int m = 0; m < 4; ++m) {
            int rg0 = rowBase + wr * 64 + m * 16 + lk * 4;
#pragma unroll
            for (int n2 = 0; n2 < 2; ++n2) {
                int d0 = n2 * 16 + l15;                 // 0..31 (freq index)
                float b0 = bias[colW + d0];
                float b2 = bias[colW + d0 + 32];
#pragma unroll
                for (int r = 0; r < 4; ++r) {
                    int rg = rg0 + r;
                    int bb = rg >> 11;
                    int s  = rg & 2047;
                    float c  = cost[s * 32 + d0];
                    float sn = sint[s * 32 + d0];
                    float a0 = acc[m][n2][r]     + b0;
                    float a2 = acc[m][n2 + 2][r] + b2;
                    float o0 = a0 * c - a2 * sn;
                    float o2 = a2 * c + a0 * sn;
                    size_t base = ((size_t)(bb * Hq + hh) * Sq + s) * 64;
                    outp[base + d0]      = f2bf(o0);
                    outp[base + d0 + 32] = f2bf(o2);
                }
            }
        }
    } else {
        // V: write transposed  vt[bh][d][s]
#pragma unroll
        for (int m = 0; m < 4; ++m) {
            int rg0 = rowBase + wr * 64 + m * 16 + lk * 4;
#pragma unroll
            for (int n = 0; n < 4; ++n) {
                int d = n * 16 + l15;
                float bb_ = bias[colW + d];
#pragma unroll
                for (int r = 0; r < 4; ++r) {
                    int rg = rg0 + r;
                    int bb = rg >> 11;
                    int s  = rg & 2047;
                    vtout[((size_t)(bb * Hq + hh) * 64 + d) * Sq + s] = f2bf(acc[m][n][r] + bb_);
                }
            }
        }
    }
}

// ---------------- flash attention ----------------
// grid: (16, 32)  block: 256 (4 waves x 32 q-rows)
__global__ __launch_bounds__(256, 2) void flash_attn(
    const ushort_t* __restrict__ qbuf, const ushort_t* __restrict__ kbuf,
    const ushort_t* __restrict__ vtbuf, ushort_t* __restrict__ abuf)
{
    __shared__ char Ks[64 * 128];        // K tile  [kv][d]   swizzled
    __shared__ char Vs[64 * 128];        // V^T tile [d][kv]  swizzled
    __shared__ char Ps[4 * 32 * 128];    // per-wave P tile [q][kv] swizzled

    const int t = threadIdx.x, lane = t & 63, wid = t >> 6;
    const int l15 = lane & 15, lk = lane >> 4;
    const int qtile = blockIdx.x, bh = blockIdx.y;
    const int bpos = bh >> 4, h = bh & 15;

    // Q fragments for this wave's 32 rows (held in registers for whole kernel)
    const ushort_t* Qp = qbuf + ((size_t)bh * Sq + qtile * 128 + wid * 32) * 64;
    short8 qf[2][2];
#pragma unroll
    for (int m = 0; m < 2; ++m)
#pragma unroll
        for (int kk = 0; kk < 2; ++kk)
            qf[m][kk] = *(const short8*)(Qp + (m * 16 + l15) * 64 + kk * 32 + lk * 8);

    floatx4 oacc[2][4] = {};
    float mrun[2][4], lrun[2][4];
#pragma unroll
    for (int m = 0; m < 2; ++m)
#pragma unroll
        for (int r = 0; r < 4; ++r) { mrun[m][r] = -INFINITY; lrun[m][r] = 0.0f; }

    const char* Kg = (const char*)kbuf  + (size_t)bh * Sq * 128;  // bytes
    const char* Vg = (const char*)vtbuf + (size_t)bh * 64 * Sq * 2;

    for (int kv0 = 0; kv0 < Sq; kv0 += 64) {
        __syncthreads();
#pragma unroll
        for (int issue = 0; issue < 2; ++issue) {
            int ldsoff = issue * 4096 + t * 16;
            int row = ldsoff >> 7;          // 128B rows
            int pb  = ldsoff & 127;
            int lb  = pb ^ ((row & 7) << 4); // pre-swizzled source -> linear LDS dest
            __builtin_amdgcn_global_load_lds(
                (const __attribute__((address_space(1))) void*)(Kg + (size_t)(kv0 + row) * 128 + lb),
                (__attribute__((address_space(3))) void*)(Ks + ldsoff), 16, 0, 0);
            __builtin_amdgcn_global_load_lds(
                (const __attribute__((address_space(1))) void*)(Vg + (size_t)row * 4096 + kv0 * 2 + lb),
                (__attribute__((address_space(3))) void*)(Vs + ldsoff), 16, 0, 0);
        }
        __syncthreads();

        // ---- S = Q K^T
        floatx4 sacc[2][4] = {};
#pragma unroll
        for (int kk = 0; kk < 2; ++kk) {
#pragma unroll
            for (int n = 0; n < 4; ++n) {
                int krow = n * 16 + l15;
                int lbyte = kk * 64 + lk * 16;
                short8 kf = *(const short8*)(Ks + krow * 128 + (lbyte ^ ((krow & 7) << 4)));
#pragma unroll
                for (int m = 0; m < 2; ++m)
                    sacc[m][n] = __builtin_amdgcn_mfma_f32_16x16x32_bf16(qf[m][kk], kf, sacc[m][n], 0, 0, 0);
            }
        }

        // ---- online softmax (wave-parallel: shfl over the 16 col-lanes)
#pragma unroll
        for (int m = 0; m < 2; ++m) {
            float pv[4][4];
#pragma unroll
            for (int r = 0; r < 4; ++r) {
                float v = fmaxf(fmaxf(sacc[m][0][r], sacc[m][1][r]),
                                fmaxf(sacc[m][2][r], sacc[m][3][r]));
#pragma unroll
                for (int off = 1; off < 16; off <<= 1) v = fmaxf(v, __shfl_xor(v, off));
                v *= 0.125f;
                float mnew = fmaxf(mrun[m][r], v);
                float corr = __expf(mrun[m][r] - mnew);
                mrun[m][r] = mnew;
                lrun[m][r] *= corr;
#pragma unroll
                for (int n = 0; n < 4; ++n) oacc[m][n][r] *= corr;
                float psum = 0.0f;
#pragma unroll
                for (int n = 0; n < 4; ++n) {
                    float p = __expf(sacc[m][n][r] * 0.125f - mnew);
                    pv[n][r] = p;
                    psum += p;
                }
#pragma unroll
                for (int off = 1; off < 16; off <<= 1) psum += __shfl_xor(psum, off);
                lrun[m][r] += psum;
            }
            // write P (bf16) to this wave's LDS region, swizzled
#pragma unroll
            for (int r = 0; r < 4; ++r) {
                int q = m * 16 + lk * 4 + r;
                char* prow = Ps + wid * 4096 + q * 128;
                int swz = (q & 7) << 4;
#pragma unroll
                for (int n = 0; n < 4; ++n)
                    *(ushort_t*)(prow + (((n * 16 + l15) * 2) ^ swz)) = f2bf(pv[n][r]);
            }
        }

        // ---- O += P V
#pragma unroll
        for (int kk = 0; kk < 2; ++kk) {
            short8 pf[2];
#pragma unroll
            for (int m = 0; m < 2; ++m) {
                int q = m * 16 + l15;
                pf[m] = *(const short8*)(Ps + wid * 4096 + q * 128 + ((kk * 64 + lk * 16) ^ ((q & 7) << 4)));
            }
#pragma unroll
            for (int n = 0; n < 4; ++n) {
                int vrow = n * 16 + l15;
                short8 vf = *(const short8*)(Vs + vrow * 128 + ((kk * 64 + lk * 16) ^ ((vrow & 7) << 4)));
#pragma unroll
                for (int m = 0; m < 2; ++m)
                    oacc[m][n] = __builtin_amdgcn_mfma_f32_16x16x32_bf16(pf[m], vf, oacc[m][n], 0, 0, 0);
            }
        }
    }

    // ---- normalize + write attn output [b][s][h*64+d] (bf16)
#pragma unroll
    for (int m = 0; m < 2; ++m)
#pragma unroll
        for (int r = 0; r < 4; ++r) {
            int srow = qtile * 128 + wid * 32 + m * 16 + lk * 4 + r;
            float inv = 1.0f / lrun[m][r];
            size_t base = ((size_t)bpos * Sq + srow) * Dq + h * 64;
#pragma unroll
            for (int n = 0; n < 4; ++n)
                abuf[base + n * 16 + l15] = f2bf(oacc[m][n][r] * inv);
        }
}

// ---------------- output projection GEMM (fp32 out) ----------------
__global__ __launch_bounds__(256, 2) void gemm_out(
    const ushort_t* __restrict__ ab, const ushort_t* __restrict__ wob,
    const float* __restrict__ bo, float* __restrict__ out)
{
    __shared__ ushort_t As[128 * 32];
    __shared__ ushort_t Bs[128 * 32];
    const int t = threadIdx.x;
    const int lane = t & 63;
    const int wid = t >> 6;
    const int l15 = lane & 15, lk = lane >> 4;
    const int wr = wid >> 1, wc = wid & 1;
    const int rowBase = blockIdx.y * 128;
    const int colBase = blockIdx.x * 128;

    floatx4 acc[4][4] = {};

    const char* Ag = (const char*)ab;
    const char* Bg = (const char*)wob;

    for (int k0 = 0; k0 < Dq; k0 += 32) {
        __syncthreads();
#pragma unroll
        for (int issue = 0; issue < 2; ++issue) {
            int ldsoff = issue * 4096 + t * 16;
            int row = ldsoff >> 6;
            int cb  = ldsoff & 63;
            __builtin_amdgcn_global_load_lds(
                (const __attribute__((address_space(1))) void*)(Ag + (size_t)(rowBase + row) * 2048 + k0 * 2 + cb),
                (__attribute__((address_space(3))) void*)((char*)As + ldsoff), 16, 0, 0);
            __builtin_amdgcn_global_load_lds(
                (const __attribute__((address_space(1))) void*)(Bg + (size_t)(colBase + row) * 2048 + k0 * 2 + cb),
                (__attribute__((address_space(3))) void*)((char*)Bs + ldsoff), 16, 0, 0);
        }
        __syncthreads();

        short8 a[4], b[4];
#pragma unroll
        for (int m = 0; m < 4; ++m)
            a[m] = *(const short8*)((const char*)As + (wr * 64 + m * 16 + l15) * 64 + lk * 16);
#pragma unroll
        for (int n = 0; n < 4; ++n)
            b[n] = *(const short8*)((const char*)Bs + (wc * 64 + n * 16 + l15) * 64 + lk * 16);
#pragma unroll
        for (int m = 0; m < 4; ++m)
#pragma unroll
            for (int n = 0; n < 4; ++n)
                acc[m][n] = __builtin_amdgcn_mfma_f32_16x16x32_bf16(a[m], b[n], acc[m][n], 0, 0, 0);
    }

    const int colW = colBase + wc * 64;
#pragma unroll
    for (int m = 0; m < 4; ++m) {
        int rg0 = rowBase + wr * 64 + m * 16 + lk * 4;
#pragma unroll
        for (int n = 0; n < 4; ++n) {
            int colg = colW + n * 16 + l15;
            float bb_ = bo[colg];
#pragma unroll
            for (int r = 0; r < 4; ++r)
                out[(size_t)(rg0 + r) * Dq + colg] = acc[m][n][r] + bb_;
        }
    }
}

extern "C" void kernel_launch(void* const* d_in, const int* in_sizes, int n_in,
                              void* d_out, int out_size, void* d_ws, size_t ws_size,
                              hipStream_t stream) {
    (void)in_sizes; (void)n_in; (void)out_size;
    const float* x  = (const float*)d_in[0];
    const float* wq = (const float*)d_in[1];
    const float* bq = (const float*)d_in[2];
    const float* wk = (const float*)d_in[3];
    const float* bk = (const float*)d_in[4];
    const float* wv = (const float*)d_in[5];
    const float* bv = (const float*)d_in[6];
    const float* wo = (const float*)d_in[7];
    const float* bo = (const float*)d_in[8];
    float* out = (float*)d_out;

    // workspace carve (all 4KB-aligned); total = 50855936 bytes (~48.5 MB)
    if (ws_size < 50855936) return;
    char* ws = (char*)d_ws;
    ushort_t* xb   = (ushort_t*)(ws + 0);          // 8 MB
    ushort_t* wqb  = (ushort_t*)(ws + 8388608);    // 2 MB
    ushort_t* wkb  = (ushort_t*)(ws + 10485760);
    ushort_t* wvb  = (ushort_t*)(ws + 12582912);
    ushort_t* wob  = (ushort_t*)(ws + 14680064);
    ushort_t* qb   = (ushort_t*)(ws + 16777216);   // 8 MB  [bh][s][64]
    ushort_t* kb   = (ushort_t*)(ws + 25165824);   // 8 MB  [bh][s][64]
    ushort_t* vtb  = (ushort_t*)(ws + 33554432);   // 8 MB  [bh][d][s]
    ushort_t* abuf = (ushort_t*)(ws + 41943040);   // 8 MB  [b][s][1024]
    float*    cost = (float*)(ws + 50331648);      // 256 KB
    float*    sint = (float*)(ws + 50593792);      // 256 KB

    cvt_f32_bf16<<<2048, 256, 0, stream>>>(x,  xb,  524288);
    cvt_f32_bf16<<<512,  256, 0, stream>>>(wq, wqb, 131072);
    cvt_f32_bf16<<<512,  256, 0, stream>>>(wk, wkb, 131072);
    cvt_f32_bf16<<<512,  256, 0, stream>>>(wv, wvb, 131072);
    cvt_f32_bf16<<<512,  256, 0, stream>>>(wo, wob, 131072);
    rope_tables<<<256, 256, 0, stream>>>(cost, sint);
    gemm_qkv<<<dim3(8, 32, 3), 256, 0, stream>>>(xb, wqb, wkb, wvb, bq, bk, bv, cost, sint, qb, kb, vtb);
    flash_attn<<<dim3(16, 32), 256, 0, stream>>>(qb, kb, vtb, abuf);
    gemm_out<<<dim3(8, 32), 256, 0, stream>>>(abuf, wob, bo, out);
}